// Round 6
// baseline (596.840 us; speedup 1.0000x reference)
//
#include <hip/hip_runtime.h>
#include <hip/hip_fp16.h>

#define U_CNT 100001
#define I_CNT 50001
#define N_CNT 150002
#define DIM 64
#define BROWS 128                           // rows per bucket
#define NB2 ((N_CNT + BROWS - 1) / BROWS)   // 1172 buckets
#define NB2R 1176                           // padded to 147*8 for serial-8 scan
#define CH 6144                             // edges per partition block
#define OUTCAP 10240                        // max records per bucket in LDS sort

__device__ inline __half2 u2h(unsigned int u) { union { unsigned int u; __half2 h; } c; c.u = u; return c.h; }
__device__ inline unsigned int h2u(__half2 h) { union { unsigned int u; __half2 h; } c; c.h = h; return c.u; }

typedef float f4_t __attribute__((ext_vector_type(4)));
typedef unsigned int u4_t __attribute__((ext_vector_type(4)));

__device__ inline float4 ntload_f4(const float4* p) {
    f4_t v = __builtin_nontemporal_load((const f4_t*)p);
    return make_float4(v.x, v.y, v.z, v.w);
}
__device__ inline void ntstore_f4(float4* p, float4 v) {
    f4_t t; t.x = v.x; t.y = v.y; t.z = v.z; t.w = v.w;
    __builtin_nontemporal_store(t, (f4_t*)p);
}
__device__ inline void ntstore_u4(uint4* p, uint4 v) {
    u4_t t; t.x = v.x; t.y = v.y; t.z = v.z; t.w = v.w;
    __builtin_nontemporal_store(t, (u4_t*)p);
}
__device__ inline unsigned int ntload_u32(const unsigned int* p) {
    return __builtin_nontemporal_load(p);
}

// LDS-privatized bucket histogram (1172 bins) — no per-row global atomics.
// Flush is staggered per block to avoid an atomic herd on bhist.
__global__ void bucket_hist(const int* __restrict__ rows, int* __restrict__ bhist,
                            int nnz) {
    __shared__ int lh[NB2];
    for (int i = threadIdx.x; i < NB2; i += blockDim.x) lh[i] = 0;
    __syncthreads();
    int stride = gridDim.x * blockDim.x;
    for (int i = blockIdx.x * blockDim.x + threadIdx.x; i < nnz; i += stride)
        atomicAdd(&lh[rows[i] >> 7], 1);
    __syncthreads();
    int off = (int)((blockIdx.x * 37u) % NB2);
    for (int ii = threadIdx.x; ii < NB2; ii += blockDim.x) {
        int i = ii + off; if (i >= NB2) i -= NB2;
        int v = lh[i];
        if (v) atomicAdd(&bhist[i], v);
    }
}

// scan of 1172 bucket totals: serial-8 per thread + 256-wide Hillis-Steele
__global__ void bucket_scan(const int* __restrict__ bhist,
                            int* __restrict__ bucket_ptr,
                            int* __restrict__ bcur) {
    __shared__ int aux[256];
    int t = threadIdx.x;
    int v[8];
    int s = 0;
    int b8 = t * 8;
    if (t < 147) {
        #pragma unroll
        for (int k = 0; k < 8; ++k) {
            int i = b8 + k;
            int d = (i < NB2) ? bhist[i] : 0;
            v[k] = s;                 // exclusive within group
            s += d;
        }
    }
    aux[t] = s;
    __syncthreads();
    for (int off = 1; off < 256; off <<= 1) {
        int x = (t >= off) ? aux[t - off] : 0;
        __syncthreads();
        aux[t] += x;
        __syncthreads();
    }
    if (t < 147) {
        int gb = (t > 0) ? aux[t - 1] : 0;
        #pragma unroll
        for (int k = 0; k < 8; ++k) {
            int i = b8 + k;
            if (i < NB2) {
                int ex = gb + v[k];
                bucket_ptr[i] = ex;
                bcur[i] = ex;
            }
        }
    }
    if (t == 255) bucket_ptr[NB2] = aux[255];
}

// phase A: block-local counting sort of a 6144-edge chunk into 1172 buckets,
// then contiguous run-writes to global staging. Record = (col<<7)|(row&127).
// Global base reservation is STAGGERED per block: all co-resident blocks
// otherwise hammer the same 1172 bcur addresses in lockstep (atomic herd).
__global__ void __launch_bounds__(256) partition_kernel(
    const int* __restrict__ rows, const int* __restrict__ cols,
    int* __restrict__ bcur, unsigned int* __restrict__ staging, int nnz)
{
    __shared__ int hist[NB2R];
    __shared__ int aux[256];
    __shared__ int gbase[NB2];
    __shared__ unsigned int recs[CH];
    __shared__ unsigned short guess[CH / 8];   // bucket of position (p & ~7)
    const int t = threadIdx.x;
    int base = blockIdx.x * CH;
    int lim = nnz - base; if (lim > CH) lim = CH;

    for (int i = t; i < NB2R; i += 256) hist[i] = 0;
    __syncthreads();
    for (int i = t; i < lim; i += 256)
        atomicAdd(&hist[rows[base + i] >> 7], 1);
    __syncthreads();
    // two-level scan: serial-8 totals -> 256-wide Hillis-Steele -> add back.
    // After this, hist[i] = inclusive end within chunk (padding bins = lim).
    {
        int s = 0;
        if (t < 147) {
            int b8 = t * 8;
            #pragma unroll
            for (int k = 0; k < 8; ++k) s += hist[b8 + k];
        }
        aux[t] = s;
    }
    __syncthreads();
    for (int off = 1; off < 256; off <<= 1) {
        int x = (t >= off) ? aux[t - off] : 0;
        __syncthreads();
        aux[t] += x;
        __syncthreads();
    }
    if (t < 147) {
        int run = (t > 0) ? aux[t - 1] : 0;
        int b8 = t * 8;
        #pragma unroll
        for (int k = 0; k < 8; ++k) {
            run += hist[b8 + k];
            hist[b8 + k] = run;        // inclusive global end
        }
    }
    __syncthreads();
    // guess table from [hist[i-1], hist[i])
    for (int i = t; i < NB2; i += 256) {
        int hi_ = hist[i];
        int lo_ = (i > 0) ? hist[i - 1] : 0;
        for (int m = (lo_ + 7) & ~7; m < hi_; m += 8)
            guess[m >> 3] = (unsigned short)i;
    }
    // global base reservation — staggered start per block
    {
        int off = (int)((blockIdx.x * 61u) % NB2);
        for (int ii = t; ii < NB2; ii += 256) {
            int i = ii + off; if (i >= NB2) i -= NB2;
            int hi_ = hist[i];
            int lo_ = (i > 0) ? hist[i - 1] : 0;
            int cnt = hi_ - lo_;
            if (cnt) gbase[i] = atomicAdd(&bcur[i], cnt);
        }
    }
    __syncthreads();
    // backward fill: hist decremented to exclusive starts
    for (int i = t; i < lim; i += 256) {
        int r = rows[base + i];
        int c = cols[base + i];
        int p = atomicAdd(&hist[r >> 7], -1) - 1;
        recs[p] = ((unsigned int)c << 7) | (unsigned int)(r & (BROWS - 1));
    }
    __syncthreads();
    // writeout: hist[i] = start of bucket i; hist[NB2] = lim (padding bin)
    for (int p = t; p < lim; p += 256) {
        unsigned int rec = recs[p];
        int lo = guess[p >> 3];
        while (hist[lo + 1] <= p) ++lo;
        staging[gbase[lo] + (p - hist[lo])] = rec;
    }
}

// phase B: one block per 128-row bucket. LDS counting sort of the whole bucket,
// then fully coalesced contiguous write of col_s (kills write amplification).
__global__ void __launch_bounds__(256) binplace_kernel(
    const int* __restrict__ bucket_ptr,
    const unsigned int* __restrict__ staging,
    unsigned int* __restrict__ col_s,
    int* __restrict__ row_ptr,
    float* __restrict__ dinv) {
    __shared__ int hist[BROWS];
    __shared__ int cur[BROWS];
    __shared__ unsigned int outb[OUTCAP];
    int b = blockIdx.x;
    int base = b << 7;
    int beg = bucket_ptr[b];
    int end = bucket_ptr[b + 1];
    int total = end - beg;
    int t = threadIdx.x;
    if (t < BROWS) hist[t] = 0;
    __syncthreads();
    for (int j = beg + t; j < end; j += 256)
        atomicAdd(&hist[staging[j] & (BROWS - 1u)], 1);
    __syncthreads();
    int cnt = (t < BROWS) ? hist[t] : 0;
    for (int off = 1; off < BROWS; off <<= 1) {
        int v = (t < BROWS && t >= off) ? hist[t - off] : 0;
        __syncthreads();
        if (t < BROWS) hist[t] += v;
        __syncthreads();
    }
    if (t < BROWS) {
        int startl = hist[t] - cnt;        // local exclusive
        cur[t] = startl;
        int r = base + t;
        if (r < N_CNT) {
            row_ptr[r] = beg + startl;
            dinv[r] = 1.0f / sqrtf((float)cnt + 1e-7f);
        }
    }
    if (b == NB2 - 1 && t == 0) row_ptr[N_CNT] = end;
    __syncthreads();
    if (total <= OUTCAP) {
        for (int j = beg + t; j < end; j += 256) {
            unsigned int rec = staging[j];
            int pos = atomicAdd(&cur[rec & (BROWS - 1u)], 1);
            outb[pos] = rec >> 7;
        }
        __syncthreads();
        for (int k = t; k < total; k += 256)
            col_s[beg + k] = outb[k];
    } else {
        // fallback (should not trigger at this distribution)
        for (int j = beg + t; j < end; j += 256) {
            unsigned int rec = staging[j];
            int pos = atomicAdd(&cur[rec & (BROWS - 1u)], 1);
            col_s[beg + pos] = rec >> 7;
        }
    }
}

// init: hs0 = fp16(dinv .* emb). No acc write — final layer composes output.
__global__ void init_kernel(const float4* __restrict__ ue,
                            const float4* __restrict__ ie,
                            const float* __restrict__ dinv,
                            uint4* __restrict__ hs) {
    int i = blockIdx.x * blockDim.x + threadIdx.x;   // over N_CNT*8
    if (i >= N_CNT * 8) return;
    int node = i >> 3;
    int s = i & 7;
    float d = dinv[node];
    size_t fo = (size_t)node * 16 + s * 2;
    float4 v0, v1;
    if (node < U_CNT) { v0 = ntload_f4(&ue[fo]); v1 = ntload_f4(&ue[fo + 1]); }
    else { size_t io = fo - (size_t)U_CNT * 16; v0 = ntload_f4(&ie[io]); v1 = ntload_f4(&ie[io + 1]); }
    uint4 h;
    h.x = h2u(__floats2half2_rn(d * v0.x, d * v0.y));
    h.y = h2u(__floats2half2_rn(d * v0.z, d * v0.w));
    h.z = h2u(__floats2half2_rn(d * v1.x, d * v1.y));
    h.w = h2u(__floats2half2_rn(d * v1.z, d * v1.w));
    hs[(size_t)node * 8 + s] = h;
}

__device__ inline void acc8(float4& a0, float4& a1, uint4 u) {
    float2 f;
    f = __half22float2(u2h(u.x)); a0.x += f.x; a0.y += f.y;
    f = __half22float2(u2h(u.y)); a0.z += f.x; a0.w += f.y;
    f = __half22float2(u2h(u.z)); a1.x += f.x; a1.y += f.y;
    f = __half22float2(u2h(u.w)); a1.z += f.x; a1.w += f.y;
}

// gather SpMM on fp16 pre-scaled hs over row range [r0, r1).
// col_s is a single-use stream -> nontemporal loads, so it doesn't evict
// the gather working set (x) from L2.
// last=0: write y = fp16(d^2 * a) only (no acc traffic).
// last=1: fuse final combine acc = 0.25*(e0 + (hs1 + hs2)/d + d*a).
__global__ void spmm_gather(const int* __restrict__ row_ptr,
                            const unsigned int* __restrict__ col_s,
                            const float* __restrict__ dinv,
                            const uint4* __restrict__ x,
                            uint4* __restrict__ y,
                            const uint4* __restrict__ h1s,
                            const float4* __restrict__ ue,
                            const float4* __restrict__ ie,
                            float4* __restrict__ acc,
                            int r0, int r1, int last) {
    int r = r0 + blockIdx.x * 32 + (threadIdx.x >> 3);
    int s = threadIdx.x & 7;
    if (r >= r1) return;
    int beg = row_ptr[r];
    int end = row_ptr[r + 1];
    float4 a0 = {0.f, 0.f, 0.f, 0.f}, a1 = {0.f, 0.f, 0.f, 0.f};
    float4 b0 = {0.f, 0.f, 0.f, 0.f}, b1 = {0.f, 0.f, 0.f, 0.f};
    int j = beg;
    // unroll-8: deepen MLP (8 independent dwordx4 gathers in flight per lane)
    for (; j + 8 <= end; j += 8) {
        unsigned int c0 = ntload_u32(&col_s[j]);
        unsigned int c1 = ntload_u32(&col_s[j + 1]);
        unsigned int c2 = ntload_u32(&col_s[j + 2]);
        unsigned int c3 = ntload_u32(&col_s[j + 3]);
        unsigned int c4 = ntload_u32(&col_s[j + 4]);
        unsigned int c5 = ntload_u32(&col_s[j + 5]);
        unsigned int c6 = ntload_u32(&col_s[j + 6]);
        unsigned int c7 = ntload_u32(&col_s[j + 7]);
        uint4 u0 = x[(size_t)c0 * 8 + s];
        uint4 u1 = x[(size_t)c1 * 8 + s];
        uint4 u2 = x[(size_t)c2 * 8 + s];
        uint4 u3 = x[(size_t)c3 * 8 + s];
        uint4 u4 = x[(size_t)c4 * 8 + s];
        uint4 u5 = x[(size_t)c5 * 8 + s];
        uint4 u6 = x[(size_t)c6 * 8 + s];
        uint4 u7 = x[(size_t)c7 * 8 + s];
        acc8(a0, a1, u0);
        acc8(b0, b1, u1);
        acc8(a0, a1, u2);
        acc8(b0, b1, u3);
        acc8(a0, a1, u4);
        acc8(b0, b1, u5);
        acc8(a0, a1, u6);
        acc8(b0, b1, u7);
    }
    for (; j + 4 <= end; j += 4) {
        unsigned int c0 = ntload_u32(&col_s[j]);
        unsigned int c1 = ntload_u32(&col_s[j + 1]);
        unsigned int c2 = ntload_u32(&col_s[j + 2]);
        unsigned int c3 = ntload_u32(&col_s[j + 3]);
        uint4 u0 = x[(size_t)c0 * 8 + s];
        uint4 u1 = x[(size_t)c1 * 8 + s];
        uint4 u2 = x[(size_t)c2 * 8 + s];
        uint4 u3 = x[(size_t)c3 * 8 + s];
        acc8(a0, a1, u0);
        acc8(b0, b1, u1);
        acc8(a0, a1, u2);
        acc8(b0, b1, u3);
    }
    for (; j < end; ++j) {
        unsigned int c0 = ntload_u32(&col_s[j]);
        uint4 u0 = x[(size_t)c0 * 8 + s];
        acc8(a0, a1, u0);
    }
    a0.x += b0.x; a0.y += b0.y; a0.z += b0.z; a0.w += b0.w;
    a1.x += b1.x; a1.y += b1.y; a1.z += b1.z; a1.w += b1.w;

    float d = dinv[r];
    if (!last) {
        float d2 = d * d;
        uint4 h;
        h.x = h2u(__floats2half2_rn(d2 * a0.x, d2 * a0.y));
        h.y = h2u(__floats2half2_rn(d2 * a0.z, d2 * a0.w));
        h.z = h2u(__floats2half2_rn(d2 * a1.x, d2 * a1.y));
        h.w = h2u(__floats2half2_rn(d2 * a1.z, d2 * a1.w));
        ntstore_u4(&y[(size_t)r * 8 + s], h);
        return;
    }

    // ---- final combine: out = 0.25*(e0 + (hs1 + hs2)*inv_d + d*a3) ----
    float inv = 1.0f / d;
    uint4 u1 = h1s[(size_t)r * 8 + s];         // hs1 = d*h1 (fp16)
    uint4 u2v = x[(size_t)r * 8 + s];          // hs2 = d*h2 (fp16)
    float4 s0 = {0.f, 0.f, 0.f, 0.f}, s1 = {0.f, 0.f, 0.f, 0.f};
    acc8(s0, s1, u1);
    acc8(s0, s1, u2v);
    size_t fo = (size_t)r * 16 + s * 2;
    float4 e0a, e0b;
    if (r < U_CNT) { e0a = ntload_f4(&ue[fo]); e0b = ntload_f4(&ue[fo + 1]); }
    else { size_t io = fo - (size_t)U_CNT * 16; e0a = ntload_f4(&ie[io]); e0b = ntload_f4(&ie[io + 1]); }
    float4 o0, o1;
    o0.x = 0.25f * (e0a.x + inv * s0.x + d * a0.x);
    o0.y = 0.25f * (e0a.y + inv * s0.y + d * a0.y);
    o0.z = 0.25f * (e0a.z + inv * s0.z + d * a0.z);
    o0.w = 0.25f * (e0a.w + inv * s0.w + d * a0.w);
    o1.x = 0.25f * (e0b.x + inv * s1.x + d * a1.x);
    o1.y = 0.25f * (e0b.y + inv * s1.y + d * a1.y);
    o1.z = 0.25f * (e0b.z + inv * s1.z + d * a1.z);
    o1.w = 0.25f * (e0b.w + inv * s1.w + d * a1.w);
    ntstore_f4(&acc[fo], o0);
    ntstore_f4(&acc[fo + 1], o1);
}

extern "C" void kernel_launch(void* const* d_in, const int* in_sizes, int n_in,
                              void* d_out, int out_size, void* d_ws, size_t ws_size,
                              hipStream_t stream) {
    const float* ue   = (const float*)d_in[0];
    const float* ie   = (const float*)d_in[1];
    const int*   rows = (const int*)d_in[2];
    const int*   cols = (const int*)d_in[3];
    int nnz = in_sizes[2];

    float* acc = (float*)d_out;

    unsigned int* ws = (unsigned int*)d_ws;
    uint4* hs0 = (uint4*)ws;                               // N*8 uint4 (fp16 hs)
    uint4* hs1 = hs0 + (size_t)N_CNT * 8;                  // N*8 uint4
    int*   row_ptr    = (int*)(hs1 + (size_t)N_CNT * 8);   // N+1
    int*   bhist      = row_ptr + (N_CNT + 1);             // NB2
    int*   bucket_ptr = bhist + NB2;                       // NB2+1
    int*   bcur       = bucket_ptr + (NB2 + 1);            // NB2
    float* dinv       = (float*)(bcur + NB2);              // N
    unsigned int* staging = (unsigned int*)(dinv + N_CNT); // nnz
    unsigned int* col_s   = staging + nnz;                 // nnz

    const int tpb = 256;

    // ---- CSR build: bucket totals (LDS hist), scan, partition, LDS-sort place ----
    hipMemsetAsync(bhist, 0, NB2 * sizeof(int), stream);
    bucket_hist<<<512, tpb, 0, stream>>>(rows, bhist, nnz);
    bucket_scan<<<1, 256, 0, stream>>>(bhist, bucket_ptr, bcur);
    partition_kernel<<<(nnz + CH - 1) / CH, tpb, 0, stream>>>(
        rows, cols, bcur, staging, nnz);
    binplace_kernel<<<NB2, tpb, 0, stream>>>(
        bucket_ptr, staging, col_s, row_ptr, dinv);

    // ---- dinv-scaled initial embeddings ----
    init_kernel<<<(N_CNT * 8 + tpb - 1) / tpb, tpb, 0, stream>>>(
        (const float4*)ue, (const float4*)ie, dinv, hs0);

    // ---- 3 propagation layers, split user/item for L2 locality ----
    uint4* cur_h = hs0;
    uint4* nxt_h = hs1;
    const int ublocks = (U_CNT + 31) / 32;
    const int iblocks = (N_CNT - U_CNT + 31) / 32;
    for (int l = 0; l < 3; ++l) {
        int last = (l == 2) ? 1 : 0;
        // after L2 swap: cur_h holds hs2, nxt_h holds hs1 (needed for combine)
        spmm_gather<<<ublocks, tpb, 0, stream>>>(
            row_ptr, col_s, dinv, cur_h, nxt_h, nxt_h,
            (const float4*)ue, (const float4*)ie, (float4*)acc, 0, U_CNT, last);
        spmm_gather<<<iblocks, tpb, 0, stream>>>(
            row_ptr, col_s, dinv, cur_h, nxt_h, nxt_h,
            (const float4*)ue, (const float4*)ie, (float4*)acc, U_CNT, N_CNT, last);
        uint4* tmp = cur_h; cur_h = nxt_h; nxt_h = tmp;
    }
}

// Round 7
// 537.442 us; speedup vs baseline: 1.1105x; 1.1105x over previous
//
#include <hip/hip_runtime.h>
#include <hip/hip_fp16.h>

#define U_CNT 100001
#define I_CNT 50001
#define N_CNT 150002
#define DIM 64
#define BROWS 128                           // rows per bucket
#define NB2 ((N_CNT + BROWS - 1) / BROWS)   // 1172 buckets
#define NB2R 1176                           // padded to 147*8 for serial-8 scan
#define CH 6144                             // edges per chunk
#define OUTCAP 10240                        // max records per bucket in LDS sort

__device__ inline __half2 u2h(unsigned int u) { union { unsigned int u; __half2 h; } c; c.u = u; return c.h; }
__device__ inline unsigned int h2u(__half2 h) { union { unsigned int u; __half2 h; } c; c.h = h; return c.u; }

typedef float f4_t __attribute__((ext_vector_type(4)));
typedef unsigned int u4_t __attribute__((ext_vector_type(4)));

__device__ inline float4 ntload_f4(const float4* p) {
    f4_t v = __builtin_nontemporal_load((const f4_t*)p);
    return make_float4(v.x, v.y, v.z, v.w);
}
__device__ inline void ntstore_f4(float4* p, float4 v) {
    f4_t t; t.x = v.x; t.y = v.y; t.z = v.z; t.w = v.w;
    __builtin_nontemporal_store(t, (f4_t*)p);
}
__device__ inline void ntstore_u4(uint4* p, uint4 v) {
    u4_t t; t.x = v.x; t.y = v.y; t.z = v.z; t.w = v.w;
    __builtin_nontemporal_store(t, (u4_t*)p);
}

// -------- deterministic-base CSR build (no global atomics anywhere) --------

// per-chunk bucket counts, written as one coalesced row: cnt[chunk][NB2R]
__global__ void count_kernel(const int* __restrict__ rows, int* __restrict__ cnt,
                             int nnz) {
    __shared__ int lh[NB2R];
    int t = threadIdx.x;
    for (int i = t; i < NB2R; i += 256) lh[i] = 0;
    __syncthreads();
    int base = blockIdx.x * CH;
    int lim = nnz - base; if (lim > CH) lim = CH;
    for (int i = t; i < lim; i += 256)
        atomicAdd(&lh[rows[base + i] >> 7], 1);
    __syncthreads();
    int* row = cnt + (size_t)blockIdx.x * NB2R;
    for (int i = t; i < NB2R; i += 256) row[i] = lh[i];
}

// per-bucket exclusive scan over chunks: ex2[bucket][chunk]; totals -> bhist
__global__ void scan_chunks(const int* __restrict__ cnt, int* __restrict__ ex2,
                            int* __restrict__ bhist, int nchunk) {
    __shared__ int aux[256];
    int b = blockIdx.x;
    int t = threadIdx.x;
    int G = (nchunk + 255) >> 8;
    int c0 = t * G;
    int c1 = c0 + G; if (c1 > nchunk) c1 = nchunk;
    int s = 0;
    for (int ch = c0; ch < c1; ++ch) s += cnt[(size_t)ch * NB2R + b];
    aux[t] = s;
    __syncthreads();
    for (int off = 1; off < 256; off <<= 1) {
        int x = (t >= off) ? aux[t - off] : 0;
        __syncthreads();
        aux[t] += x;
        __syncthreads();
    }
    int run = (t > 0) ? aux[t - 1] : 0;
    for (int ch = c0; ch < c1; ++ch) {
        int v = cnt[(size_t)ch * NB2R + b];
        ex2[(size_t)b * nchunk + ch] = run;
        run += v;
    }
    if (t == 255) bhist[b] = aux[255];
}

// scan of 1172 bucket totals: serial-8 per thread + 256-wide Hillis-Steele
__global__ void bucket_scan(const int* __restrict__ bhist,
                            int* __restrict__ bucket_ptr) {
    __shared__ int aux[256];
    int t = threadIdx.x;
    int v[8];
    int s = 0;
    int b8 = t * 8;
    if (t < 147) {
        #pragma unroll
        for (int k = 0; k < 8; ++k) {
            int i = b8 + k;
            int d = (i < NB2) ? bhist[i] : 0;
            v[k] = s;                 // exclusive within group
            s += d;
        }
    }
    aux[t] = s;
    __syncthreads();
    for (int off = 1; off < 256; off <<= 1) {
        int x = (t >= off) ? aux[t - off] : 0;
        __syncthreads();
        aux[t] += x;
        __syncthreads();
    }
    if (t < 147) {
        int gb = (t > 0) ? aux[t - 1] : 0;
        #pragma unroll
        for (int k = 0; k < 8; ++k) {
            int i = b8 + k;
            if (i < NB2) bucket_ptr[i] = gb + v[k];
        }
    }
    if (t == 255) bucket_ptr[NB2] = aux[255];
}

// fill: LDS counting sort of a 6144-edge chunk, bases READ (not reserved).
// Record = (col<<7)|(row&127). hist row loaded from cnt (no first edge pass).
__global__ void __launch_bounds__(256) fill_kernel(
    const int* __restrict__ rows, const int* __restrict__ cols,
    const int* __restrict__ cnt, const int* __restrict__ ex2,
    const int* __restrict__ bucket_ptr,
    unsigned int* __restrict__ staging, int nnz, int nchunk)
{
    __shared__ int hist[NB2R];
    __shared__ int aux[256];
    __shared__ int gbase[NB2];
    __shared__ unsigned int recs[CH];
    __shared__ unsigned short guess[CH / 8];   // bucket of position (p & ~7)
    const int t = threadIdx.x;
    int chunk = blockIdx.x;
    int base = chunk * CH;
    int lim = nnz - base; if (lim > CH) lim = CH;

    const int* crow = cnt + (size_t)chunk * NB2R;
    for (int i = t; i < NB2R; i += 256) hist[i] = crow[i];
    // deterministic global bases: bucket_ptr + exclusive-scan-over-chunks
    for (int i = t; i < NB2; i += 256)
        gbase[i] = bucket_ptr[i] + ex2[(size_t)i * nchunk + chunk];
    __syncthreads();
    // two-level scan: serial-8 totals -> 256-wide Hillis-Steele -> add back.
    // After this, hist[i] = inclusive end within chunk (padding bins = lim).
    {
        int s = 0;
        if (t < 147) {
            int b8 = t * 8;
            #pragma unroll
            for (int k = 0; k < 8; ++k) s += hist[b8 + k];
        }
        aux[t] = s;
    }
    __syncthreads();
    for (int off = 1; off < 256; off <<= 1) {
        int x = (t >= off) ? aux[t - off] : 0;
        __syncthreads();
        aux[t] += x;
        __syncthreads();
    }
    if (t < 147) {
        int run = (t > 0) ? aux[t - 1] : 0;
        int b8 = t * 8;
        #pragma unroll
        for (int k = 0; k < 8; ++k) {
            run += hist[b8 + k];
            hist[b8 + k] = run;        // inclusive global end
        }
    }
    __syncthreads();
    // guess table from [hist[i-1], hist[i])
    for (int i = t; i < NB2; i += 256) {
        int hi_ = hist[i];
        int lo_ = (i > 0) ? hist[i - 1] : 0;
        for (int m = (lo_ + 7) & ~7; m < hi_; m += 8)
            guess[m >> 3] = (unsigned short)i;
    }
    __syncthreads();
    // backward fill: hist decremented to exclusive starts
    for (int i = t; i < lim; i += 256) {
        int r = rows[base + i];
        int c = cols[base + i];
        int p = atomicAdd(&hist[r >> 7], -1) - 1;
        recs[p] = ((unsigned int)c << 7) | (unsigned int)(r & (BROWS - 1));
    }
    __syncthreads();
    // writeout: hist[i] = start of bucket i; padding bins hold lim
    for (int p = t; p < lim; p += 256) {
        unsigned int rec = recs[p];
        int lo = guess[p >> 3];
        while (hist[lo + 1] <= p) ++lo;
        staging[gbase[lo] + (p - hist[lo])] = rec;
    }
}

// phase B: one block per 128-row bucket. LDS counting sort of the whole bucket,
// then fully coalesced contiguous write of col_s (kills write amplification).
__global__ void __launch_bounds__(256) binplace_kernel(
    const int* __restrict__ bucket_ptr,
    const unsigned int* __restrict__ staging,
    unsigned int* __restrict__ col_s,
    int* __restrict__ row_ptr,
    float* __restrict__ dinv) {
    __shared__ int hist[BROWS];
    __shared__ int cur[BROWS];
    __shared__ unsigned int outb[OUTCAP];
    int b = blockIdx.x;
    int base = b << 7;
    int beg = bucket_ptr[b];
    int end = bucket_ptr[b + 1];
    int total = end - beg;
    int t = threadIdx.x;
    if (t < BROWS) hist[t] = 0;
    __syncthreads();
    for (int j = beg + t; j < end; j += 256)
        atomicAdd(&hist[staging[j] & (BROWS - 1u)], 1);
    __syncthreads();
    int cnt = (t < BROWS) ? hist[t] : 0;
    for (int off = 1; off < BROWS; off <<= 1) {
        int v = (t < BROWS && t >= off) ? hist[t - off] : 0;
        __syncthreads();
        if (t < BROWS) hist[t] += v;
        __syncthreads();
    }
    if (t < BROWS) {
        int startl = hist[t] - cnt;        // local exclusive
        cur[t] = startl;
        int r = base + t;
        if (r < N_CNT) {
            row_ptr[r] = beg + startl;
            dinv[r] = 1.0f / sqrtf((float)cnt + 1e-7f);
        }
    }
    if (b == NB2 - 1 && t == 0) row_ptr[N_CNT] = end;
    __syncthreads();
    if (total <= OUTCAP) {
        for (int j = beg + t; j < end; j += 256) {
            unsigned int rec = staging[j];
            int pos = atomicAdd(&cur[rec & (BROWS - 1u)], 1);
            outb[pos] = rec >> 7;
        }
        __syncthreads();
        for (int k = t; k < total; k += 256)
            col_s[beg + k] = outb[k];
    } else {
        // fallback (should not trigger at this distribution)
        for (int j = beg + t; j < end; j += 256) {
            unsigned int rec = staging[j];
            int pos = atomicAdd(&cur[rec & (BROWS - 1u)], 1);
            col_s[beg + pos] = rec >> 7;
        }
    }
}

// init: hs0 = fp16(dinv .* emb). No acc write — final layer composes output.
__global__ void init_kernel(const float4* __restrict__ ue,
                            const float4* __restrict__ ie,
                            const float* __restrict__ dinv,
                            uint4* __restrict__ hs) {
    int i = blockIdx.x * blockDim.x + threadIdx.x;   // over N_CNT*8
    if (i >= N_CNT * 8) return;
    int node = i >> 3;
    int s = i & 7;
    float d = dinv[node];
    size_t fo = (size_t)node * 16 + s * 2;
    float4 v0, v1;
    if (node < U_CNT) { v0 = ntload_f4(&ue[fo]); v1 = ntload_f4(&ue[fo + 1]); }
    else { size_t io = fo - (size_t)U_CNT * 16; v0 = ntload_f4(&ie[io]); v1 = ntload_f4(&ie[io + 1]); }
    uint4 h;
    h.x = h2u(__floats2half2_rn(d * v0.x, d * v0.y));
    h.y = h2u(__floats2half2_rn(d * v0.z, d * v0.w));
    h.z = h2u(__floats2half2_rn(d * v1.x, d * v1.y));
    h.w = h2u(__floats2half2_rn(d * v1.z, d * v1.w));
    hs[(size_t)node * 8 + s] = h;
}

__device__ inline void acc8(float4& a0, float4& a1, uint4 u) {
    float2 f;
    f = __half22float2(u2h(u.x)); a0.x += f.x; a0.y += f.y;
    f = __half22float2(u2h(u.y)); a0.z += f.x; a0.w += f.y;
    f = __half22float2(u2h(u.z)); a1.x += f.x; a1.y += f.y;
    f = __half22float2(u2h(u.w)); a1.z += f.x; a1.w += f.y;
}

// gather SpMM on fp16 pre-scaled hs over row range [r0, r1).
// col_s loads are PLAIN (broadcast across 8 lanes + line reuse across rows —
// nt hint here cost ~30us in round 6).
// last=0: write y = fp16(d^2 * a) only (no acc traffic).
// last=1: fuse final combine acc = 0.25*(e0 + (hs1 + hs2)/d + d*a).
__global__ void spmm_gather(const int* __restrict__ row_ptr,
                            const unsigned int* __restrict__ col_s,
                            const float* __restrict__ dinv,
                            const uint4* __restrict__ x,
                            uint4* __restrict__ y,
                            const uint4* __restrict__ h1s,
                            const float4* __restrict__ ue,
                            const float4* __restrict__ ie,
                            float4* __restrict__ acc,
                            int r0, int r1, int last) {
    int r = r0 + blockIdx.x * 32 + (threadIdx.x >> 3);
    int s = threadIdx.x & 7;
    if (r >= r1) return;
    int beg = row_ptr[r];
    int end = row_ptr[r + 1];
    float4 a0 = {0.f, 0.f, 0.f, 0.f}, a1 = {0.f, 0.f, 0.f, 0.f};
    float4 b0 = {0.f, 0.f, 0.f, 0.f}, b1 = {0.f, 0.f, 0.f, 0.f};
    int j = beg;
    // unroll-8: deepen MLP (8 independent dwordx4 gathers in flight per lane)
    for (; j + 8 <= end; j += 8) {
        unsigned int c0 = col_s[j];
        unsigned int c1 = col_s[j + 1];
        unsigned int c2 = col_s[j + 2];
        unsigned int c3 = col_s[j + 3];
        unsigned int c4 = col_s[j + 4];
        unsigned int c5 = col_s[j + 5];
        unsigned int c6 = col_s[j + 6];
        unsigned int c7 = col_s[j + 7];
        uint4 u0 = x[(size_t)c0 * 8 + s];
        uint4 u1 = x[(size_t)c1 * 8 + s];
        uint4 u2 = x[(size_t)c2 * 8 + s];
        uint4 u3 = x[(size_t)c3 * 8 + s];
        uint4 u4 = x[(size_t)c4 * 8 + s];
        uint4 u5 = x[(size_t)c5 * 8 + s];
        uint4 u6 = x[(size_t)c6 * 8 + s];
        uint4 u7 = x[(size_t)c7 * 8 + s];
        acc8(a0, a1, u0);
        acc8(b0, b1, u1);
        acc8(a0, a1, u2);
        acc8(b0, b1, u3);
        acc8(a0, a1, u4);
        acc8(b0, b1, u5);
        acc8(a0, a1, u6);
        acc8(b0, b1, u7);
    }
    for (; j + 4 <= end; j += 4) {
        unsigned int c0 = col_s[j];
        unsigned int c1 = col_s[j + 1];
        unsigned int c2 = col_s[j + 2];
        unsigned int c3 = col_s[j + 3];
        uint4 u0 = x[(size_t)c0 * 8 + s];
        uint4 u1 = x[(size_t)c1 * 8 + s];
        uint4 u2 = x[(size_t)c2 * 8 + s];
        uint4 u3 = x[(size_t)c3 * 8 + s];
        acc8(a0, a1, u0);
        acc8(b0, b1, u1);
        acc8(a0, a1, u2);
        acc8(b0, b1, u3);
    }
    for (; j < end; ++j) {
        unsigned int c0 = col_s[j];
        uint4 u0 = x[(size_t)c0 * 8 + s];
        acc8(a0, a1, u0);
    }
    a0.x += b0.x; a0.y += b0.y; a0.z += b0.z; a0.w += b0.w;
    a1.x += b1.x; a1.y += b1.y; a1.z += b1.z; a1.w += b1.w;

    float d = dinv[r];
    if (!last) {
        float d2 = d * d;
        uint4 h;
        h.x = h2u(__floats2half2_rn(d2 * a0.x, d2 * a0.y));
        h.y = h2u(__floats2half2_rn(d2 * a0.z, d2 * a0.w));
        h.z = h2u(__floats2half2_rn(d2 * a1.x, d2 * a1.y));
        h.w = h2u(__floats2half2_rn(d2 * a1.z, d2 * a1.w));
        ntstore_u4(&y[(size_t)r * 8 + s], h);
        return;
    }

    // ---- final combine: out = 0.25*(e0 + (hs1 + hs2)*inv_d + d*a3) ----
    float inv = 1.0f / d;
    uint4 u1 = h1s[(size_t)r * 8 + s];         // hs1 = d*h1 (fp16)
    uint4 u2v = x[(size_t)r * 8 + s];          // hs2 = d*h2 (fp16)
    float4 s0 = {0.f, 0.f, 0.f, 0.f}, s1 = {0.f, 0.f, 0.f, 0.f};
    acc8(s0, s1, u1);
    acc8(s0, s1, u2v);
    size_t fo = (size_t)r * 16 + s * 2;
    float4 e0a, e0b;
    if (r < U_CNT) { e0a = ntload_f4(&ue[fo]); e0b = ntload_f4(&ue[fo + 1]); }
    else { size_t io = fo - (size_t)U_CNT * 16; e0a = ntload_f4(&ie[io]); e0b = ntload_f4(&ie[io + 1]); }
    float4 o0, o1;
    o0.x = 0.25f * (e0a.x + inv * s0.x + d * a0.x);
    o0.y = 0.25f * (e0a.y + inv * s0.y + d * a0.y);
    o0.z = 0.25f * (e0a.z + inv * s0.z + d * a0.z);
    o0.w = 0.25f * (e0a.w + inv * s0.w + d * a0.w);
    o1.x = 0.25f * (e0b.x + inv * s1.x + d * a1.x);
    o1.y = 0.25f * (e0b.y + inv * s1.y + d * a1.y);
    o1.z = 0.25f * (e0b.z + inv * s1.z + d * a1.z);
    o1.w = 0.25f * (e0b.w + inv * s1.w + d * a1.w);
    ntstore_f4(&acc[fo], o0);
    ntstore_f4(&acc[fo + 1], o1);
}

extern "C" void kernel_launch(void* const* d_in, const int* in_sizes, int n_in,
                              void* d_out, int out_size, void* d_ws, size_t ws_size,
                              hipStream_t stream) {
    const float* ue   = (const float*)d_in[0];
    const float* ie   = (const float*)d_in[1];
    const int*   rows = (const int*)d_in[2];
    const int*   cols = (const int*)d_in[3];
    int nnz = in_sizes[2];
    int nchunk = (nnz + CH - 1) / CH;

    float* acc = (float*)d_out;

    unsigned int* ws = (unsigned int*)d_ws;
    uint4* hs0 = (uint4*)ws;                               // N*8 uint4 (fp16 hs)
    uint4* hs1 = hs0 + (size_t)N_CNT * 8;                  // N*8 uint4
    int*   row_ptr    = (int*)(hs1 + (size_t)N_CNT * 8);   // N+1
    int*   bhist      = row_ptr + (N_CNT + 1);             // NB2
    int*   bucket_ptr = bhist + NB2;                       // NB2+1
    float* dinv       = (float*)(bucket_ptr + NB2 + 1);    // N
    unsigned int* staging = (unsigned int*)(dinv + N_CNT); // nnz
    unsigned int* col_s   = staging + nnz;                 // nnz
    // cnt + ex2 overlay the col_s region (dead before binplace writes col_s)
    int* cnt = (int*)col_s;                                // nchunk*NB2R
    int* ex2 = cnt + (size_t)nchunk * NB2R;                // NB2*nchunk

    const int tpb = 256;

    // ---- CSR build: counts -> chunk scans -> bucket scan -> fill -> place ----
    count_kernel<<<nchunk, tpb, 0, stream>>>(rows, cnt, nnz);
    scan_chunks<<<NB2, tpb, 0, stream>>>(cnt, ex2, bhist, nchunk);
    bucket_scan<<<1, tpb, 0, stream>>>(bhist, bucket_ptr);
    fill_kernel<<<nchunk, tpb, 0, stream>>>(
        rows, cols, cnt, ex2, bucket_ptr, staging, nnz, nchunk);
    binplace_kernel<<<NB2, tpb, 0, stream>>>(
        bucket_ptr, staging, col_s, row_ptr, dinv);

    // ---- dinv-scaled initial embeddings ----
    init_kernel<<<(N_CNT * 8 + tpb - 1) / tpb, tpb, 0, stream>>>(
        (const float4*)ue, (const float4*)ie, dinv, hs0);

    // ---- 3 propagation layers, split user/item for L2 locality ----
    uint4* cur_h = hs0;
    uint4* nxt_h = hs1;
    const int ublocks = (U_CNT + 31) / 32;
    const int iblocks = (N_CNT - U_CNT + 31) / 32;
    for (int l = 0; l < 3; ++l) {
        int last = (l == 2) ? 1 : 0;
        // after L2 swap: cur_h holds hs2, nxt_h holds hs1 (needed for combine)
        spmm_gather<<<ublocks, tpb, 0, stream>>>(
            row_ptr, col_s, dinv, cur_h, nxt_h, nxt_h,
            (const float4*)ue, (const float4*)ie, (float4*)acc, 0, U_CNT, last);
        spmm_gather<<<iblocks, tpb, 0, stream>>>(
            row_ptr, col_s, dinv, cur_h, nxt_h, nxt_h,
            (const float4*)ue, (const float4*)ie, (float4*)acc, U_CNT, N_CNT, last);
        uint4* tmp = cur_h; cur_h = nxt_h; nxt_h = tmp;
    }
}

// Round 8
// 507.187 us; speedup vs baseline: 1.1768x; 1.0597x over previous
//
#include <hip/hip_runtime.h>
#include <hip/hip_fp16.h>

#define U_CNT 100001
#define I_CNT 50001
#define N_CNT 150002
#define DIM 64
#define BROWS 128                           // rows per bucket
#define NB2 ((N_CNT + BROWS - 1) / BROWS)   // 1172 buckets
#define NB2R 1176                           // padded to 147*8 for serial-8 scan
#define CH 6144                             // edges per chunk
#define OUTCAP 10240                        // max records per bucket in LDS sort
#define CBSHIFT 14                          // 16384 nodes (2 MB fp16) per col block
#define NBLK 10                             // ceil(150002 / 16384)
#define NBINS (BROWS * NBLK)                // 1280 sort bins in binplace

__device__ inline __half2 u2h(unsigned int u) { union { unsigned int u; __half2 h; } c; c.u = u; return c.h; }
__device__ inline unsigned int h2u(__half2 h) { union { unsigned int u; __half2 h; } c; c.h = h; return c.u; }

typedef float f4_t __attribute__((ext_vector_type(4)));
typedef unsigned int u4_t __attribute__((ext_vector_type(4)));

__device__ inline float4 ntload_f4(const float4* p) {
    f4_t v = __builtin_nontemporal_load((const f4_t*)p);
    return make_float4(v.x, v.y, v.z, v.w);
}
__device__ inline void ntstore_f4(float4* p, float4 v) {
    f4_t t; t.x = v.x; t.y = v.y; t.z = v.z; t.w = v.w;
    __builtin_nontemporal_store(t, (f4_t*)p);
}
__device__ inline void ntstore_u4(uint4* p, uint4 v) {
    u4_t t; t.x = v.x; t.y = v.y; t.z = v.z; t.w = v.w;
    __builtin_nontemporal_store(t, (u4_t*)p);
}

// -------- deterministic-base CSR build (no global atomics anywhere) --------

// per-chunk bucket counts, written as one coalesced row: cnt[chunk][NB2R]
__global__ void count_kernel(const int* __restrict__ rows, int* __restrict__ cnt,
                             int nnz) {
    __shared__ int lh[NB2R];
    int t = threadIdx.x;
    for (int i = t; i < NB2R; i += 256) lh[i] = 0;
    __syncthreads();
    int base = blockIdx.x * CH;
    int lim = nnz - base; if (lim > CH) lim = CH;
    for (int i = t; i < lim; i += 256)
        atomicAdd(&lh[rows[base + i] >> 7], 1);
    __syncthreads();
    int* row = cnt + (size_t)blockIdx.x * NB2R;
    for (int i = t; i < NB2R; i += 256) row[i] = lh[i];
}

// per-bucket exclusive scan over chunks: ex2[bucket][chunk]; totals -> bhist
__global__ void scan_chunks(const int* __restrict__ cnt, int* __restrict__ ex2,
                            int* __restrict__ bhist, int nchunk) {
    __shared__ int aux[256];
    int b = blockIdx.x;
    int t = threadIdx.x;
    int G = (nchunk + 255) >> 8;
    int c0 = t * G;
    int c1 = c0 + G; if (c1 > nchunk) c1 = nchunk;
    int s = 0;
    for (int ch = c0; ch < c1; ++ch) s += cnt[(size_t)ch * NB2R + b];
    aux[t] = s;
    __syncthreads();
    for (int off = 1; off < 256; off <<= 1) {
        int x = (t >= off) ? aux[t - off] : 0;
        __syncthreads();
        aux[t] += x;
        __syncthreads();
    }
    int run = (t > 0) ? aux[t - 1] : 0;
    for (int ch = c0; ch < c1; ++ch) {
        int v = cnt[(size_t)ch * NB2R + b];
        ex2[(size_t)b * nchunk + ch] = run;
        run += v;
    }
    if (t == 255) bhist[b] = aux[255];
}

// scan of 1172 bucket totals: serial-8 per thread + 256-wide Hillis-Steele
__global__ void bucket_scan(const int* __restrict__ bhist,
                            int* __restrict__ bucket_ptr) {
    __shared__ int aux[256];
    int t = threadIdx.x;
    int v[8];
    int s = 0;
    int b8 = t * 8;
    if (t < 147) {
        #pragma unroll
        for (int k = 0; k < 8; ++k) {
            int i = b8 + k;
            int d = (i < NB2) ? bhist[i] : 0;
            v[k] = s;                 // exclusive within group
            s += d;
        }
    }
    aux[t] = s;
    __syncthreads();
    for (int off = 1; off < 256; off <<= 1) {
        int x = (t >= off) ? aux[t - off] : 0;
        __syncthreads();
        aux[t] += x;
        __syncthreads();
    }
    if (t < 147) {
        int gb = (t > 0) ? aux[t - 1] : 0;
        #pragma unroll
        for (int k = 0; k < 8; ++k) {
            int i = b8 + k;
            if (i < NB2) bucket_ptr[i] = gb + v[k];
        }
    }
    if (t == 255) bucket_ptr[NB2] = aux[255];
}

// fill: LDS counting sort of a 6144-edge chunk, bases READ (not reserved).
// Record = (col<<7)|(row&127). hist row loaded from cnt (no first edge pass).
__global__ void __launch_bounds__(256) fill_kernel(
    const int* __restrict__ rows, const int* __restrict__ cols,
    const int* __restrict__ cnt, const int* __restrict__ ex2,
    const int* __restrict__ bucket_ptr,
    unsigned int* __restrict__ staging, int nnz, int nchunk)
{
    __shared__ int hist[NB2R];
    __shared__ int aux[256];
    __shared__ int gbase[NB2];
    __shared__ unsigned int recs[CH];
    __shared__ unsigned short guess[CH / 8];   // bucket of position (p & ~7)
    const int t = threadIdx.x;
    int chunk = blockIdx.x;
    int base = chunk * CH;
    int lim = nnz - base; if (lim > CH) lim = CH;

    const int* crow = cnt + (size_t)chunk * NB2R;
    for (int i = t; i < NB2R; i += 256) hist[i] = crow[i];
    // deterministic global bases: bucket_ptr + exclusive-scan-over-chunks
    for (int i = t; i < NB2; i += 256)
        gbase[i] = bucket_ptr[i] + ex2[(size_t)i * nchunk + chunk];
    __syncthreads();
    // two-level scan: serial-8 totals -> 256-wide Hillis-Steele -> add back.
    // After this, hist[i] = inclusive end within chunk (padding bins = lim).
    {
        int s = 0;
        if (t < 147) {
            int b8 = t * 8;
            #pragma unroll
            for (int k = 0; k < 8; ++k) s += hist[b8 + k];
        }
        aux[t] = s;
    }
    __syncthreads();
    for (int off = 1; off < 256; off <<= 1) {
        int x = (t >= off) ? aux[t - off] : 0;
        __syncthreads();
        aux[t] += x;
        __syncthreads();
    }
    if (t < 147) {
        int run = (t > 0) ? aux[t - 1] : 0;
        int b8 = t * 8;
        #pragma unroll
        for (int k = 0; k < 8; ++k) {
            run += hist[b8 + k];
            hist[b8 + k] = run;        // inclusive global end
        }
    }
    __syncthreads();
    // guess table from [hist[i-1], hist[i])
    for (int i = t; i < NB2; i += 256) {
        int hi_ = hist[i];
        int lo_ = (i > 0) ? hist[i - 1] : 0;
        for (int m = (lo_ + 7) & ~7; m < hi_; m += 8)
            guess[m >> 3] = (unsigned short)i;
    }
    __syncthreads();
    // backward fill: hist decremented to exclusive starts
    for (int i = t; i < lim; i += 256) {
        int r = rows[base + i];
        int c = cols[base + i];
        int p = atomicAdd(&hist[r >> 7], -1) - 1;
        recs[p] = ((unsigned int)c << 7) | (unsigned int)(r & (BROWS - 1));
    }
    __syncthreads();
    // writeout: hist[i] = start of bucket i; padding bins hold lim
    for (int p = t; p < lim; p += 256) {
        unsigned int rec = recs[p];
        int lo = guess[p >> 3];
        while (hist[lo + 1] <= p) ++lo;
        staging[gbase[lo] + (p - hist[lo])] = rec;
    }
}

// phase B: one block per 128-row bucket. LDS counting sort of the whole bucket
// with key = (row, col>>CBSHIFT): within each row, edges end up SORTED BY
// 2-MB COLUMN BLOCK, which makes the spmm gather walk L2-resident blocks.
// Fully coalesced contiguous write of col_s.
__global__ void __launch_bounds__(256) binplace_kernel(
    const int* __restrict__ bucket_ptr,
    const unsigned int* __restrict__ staging,
    unsigned int* __restrict__ col_s,
    int* __restrict__ row_ptr,
    float* __restrict__ dinv) {
    __shared__ int hist[NBINS + 1];
    __shared__ int cur[NBINS];
    __shared__ unsigned int outb[OUTCAP];
    int b = blockIdx.x;
    int base = b << 7;
    int beg = bucket_ptr[b];
    int end = bucket_ptr[b + 1];
    int total = end - beg;
    int t = threadIdx.x;
    for (int i = t; i < NBINS; i += 256) hist[i] = 0;
    __syncthreads();
    for (int j = beg + t; j < end; j += 256) {
        unsigned int rec = staging[j];
        int key = (int)(rec & (BROWS - 1u)) * NBLK + (int)(rec >> (7 + CBSHIFT));
        atomicAdd(&hist[key], 1);
    }
    __syncthreads();
    // scan NBINS = 1280 bins: serial-5 per thread + 256-wide Hillis-Steele
    {
        __shared__ int aux[256];
        int b5 = t * (NBINS / 256);
        int s = 0;
        #pragma unroll
        for (int k = 0; k < NBINS / 256; ++k) s += hist[b5 + k];
        aux[t] = s;
        __syncthreads();
        for (int off = 1; off < 256; off <<= 1) {
            int x = (t >= off) ? aux[t - off] : 0;
            __syncthreads();
            aux[t] += x;
            __syncthreads();
        }
        int run = (t > 0) ? aux[t - 1] : 0;
        #pragma unroll
        for (int k = 0; k < NBINS / 256; ++k) {
            int v = hist[b5 + k];
            hist[b5 + k] = run;        // exclusive start
            run += v;
        }
        if (t == 255) hist[NBINS] = aux[255];
    }
    __syncthreads();
    if (t < BROWS) {
        int startl = hist[t * NBLK];
        int cntr = hist[(t + 1) * NBLK] - startl;
        int r = base + t;
        if (r < N_CNT) {
            row_ptr[r] = beg + startl;
            dinv[r] = 1.0f / sqrtf((float)cntr + 1e-7f);
        }
    }
    for (int i = t; i < NBINS; i += 256) cur[i] = hist[i];
    if (b == NB2 - 1 && t == 0) row_ptr[N_CNT] = end;
    __syncthreads();
    if (total <= OUTCAP) {
        for (int j = beg + t; j < end; j += 256) {
            unsigned int rec = staging[j];
            int key = (int)(rec & (BROWS - 1u)) * NBLK + (int)(rec >> (7 + CBSHIFT));
            int pos = atomicAdd(&cur[key], 1);
            outb[pos] = rec >> 7;
        }
        __syncthreads();
        for (int k = t; k < total; k += 256)
            col_s[beg + k] = outb[k];
    } else {
        // fallback (should not trigger at this distribution)
        for (int j = beg + t; j < end; j += 256) {
            unsigned int rec = staging[j];
            int key = (int)(rec & (BROWS - 1u)) * NBLK + (int)(rec >> (7 + CBSHIFT));
            int pos = atomicAdd(&cur[key], 1);
            col_s[beg + pos] = rec >> 7;
        }
    }
}

// init: hs0 = fp16(dinv .* emb). No acc write — final layer composes output.
__global__ void init_kernel(const float4* __restrict__ ue,
                            const float4* __restrict__ ie,
                            const float* __restrict__ dinv,
                            uint4* __restrict__ hs) {
    int i = blockIdx.x * blockDim.x + threadIdx.x;   // over N_CNT*8
    if (i >= N_CNT * 8) return;
    int node = i >> 3;
    int s = i & 7;
    float d = dinv[node];
    size_t fo = (size_t)node * 16 + s * 2;
    float4 v0, v1;
    if (node < U_CNT) { v0 = ntload_f4(&ue[fo]); v1 = ntload_f4(&ue[fo + 1]); }
    else { size_t io = fo - (size_t)U_CNT * 16; v0 = ntload_f4(&ie[io]); v1 = ntload_f4(&ie[io + 1]); }
    uint4 h;
    h.x = h2u(__floats2half2_rn(d * v0.x, d * v0.y));
    h.y = h2u(__floats2half2_rn(d * v0.z, d * v0.w));
    h.z = h2u(__floats2half2_rn(d * v1.x, d * v1.y));
    h.w = h2u(__floats2half2_rn(d * v1.z, d * v1.w));
    hs[(size_t)node * 8 + s] = h;
}

__device__ inline void acc8(float4& a0, float4& a1, uint4 u) {
    float2 f;
    f = __half22float2(u2h(u.x)); a0.x += f.x; a0.y += f.y;
    f = __half22float2(u2h(u.y)); a0.z += f.x; a0.w += f.y;
    f = __half22float2(u2h(u.z)); a1.x += f.x; a1.y += f.y;
    f = __half22float2(u2h(u.w)); a1.z += f.x; a1.w += f.y;
}

// gather SpMM on fp16 pre-scaled hs over row range [r0, r1).
// Edges are sorted by column block within each row (binplace key), so the
// concurrent gather working set is one ~2 MB block -> per-XCD L2 resident.
// last=0: write y = fp16(d^2 * a) only (no acc traffic).
// last=1: fuse final combine acc = 0.25*(e0 + (hs1 + hs2)/d + d*a).
__global__ void spmm_gather(const int* __restrict__ row_ptr,
                            const unsigned int* __restrict__ col_s,
                            const float* __restrict__ dinv,
                            const uint4* __restrict__ x,
                            uint4* __restrict__ y,
                            const uint4* __restrict__ h1s,
                            const float4* __restrict__ ue,
                            const float4* __restrict__ ie,
                            float4* __restrict__ acc,
                            int r0, int r1, int last) {
    int r = r0 + blockIdx.x * 32 + (threadIdx.x >> 3);
    int s = threadIdx.x & 7;
    if (r >= r1) return;
    int beg = row_ptr[r];
    int end = row_ptr[r + 1];
    float4 a0 = {0.f, 0.f, 0.f, 0.f}, a1 = {0.f, 0.f, 0.f, 0.f};
    float4 b0 = {0.f, 0.f, 0.f, 0.f}, b1 = {0.f, 0.f, 0.f, 0.f};
    int j = beg;
    // unroll-8: deepen MLP (8 independent dwordx4 gathers in flight per lane)
    for (; j + 8 <= end; j += 8) {
        unsigned int c0 = col_s[j];
        unsigned int c1 = col_s[j + 1];
        unsigned int c2 = col_s[j + 2];
        unsigned int c3 = col_s[j + 3];
        unsigned int c4 = col_s[j + 4];
        unsigned int c5 = col_s[j + 5];
        unsigned int c6 = col_s[j + 6];
        unsigned int c7 = col_s[j + 7];
        uint4 u0 = x[(size_t)c0 * 8 + s];
        uint4 u1 = x[(size_t)c1 * 8 + s];
        uint4 u2 = x[(size_t)c2 * 8 + s];
        uint4 u3 = x[(size_t)c3 * 8 + s];
        uint4 u4 = x[(size_t)c4 * 8 + s];
        uint4 u5 = x[(size_t)c5 * 8 + s];
        uint4 u6 = x[(size_t)c6 * 8 + s];
        uint4 u7 = x[(size_t)c7 * 8 + s];
        acc8(a0, a1, u0);
        acc8(b0, b1, u1);
        acc8(a0, a1, u2);
        acc8(b0, b1, u3);
        acc8(a0, a1, u4);
        acc8(b0, b1, u5);
        acc8(a0, a1, u6);
        acc8(b0, b1, u7);
    }
    for (; j + 4 <= end; j += 4) {
        unsigned int c0 = col_s[j];
        unsigned int c1 = col_s[j + 1];
        unsigned int c2 = col_s[j + 2];
        unsigned int c3 = col_s[j + 3];
        uint4 u0 = x[(size_t)c0 * 8 + s];
        uint4 u1 = x[(size_t)c1 * 8 + s];
        uint4 u2 = x[(size_t)c2 * 8 + s];
        uint4 u3 = x[(size_t)c3 * 8 + s];
        acc8(a0, a1, u0);
        acc8(b0, b1, u1);
        acc8(a0, a1, u2);
        acc8(b0, b1, u3);
    }
    for (; j < end; ++j) {
        unsigned int c0 = col_s[j];
        uint4 u0 = x[(size_t)c0 * 8 + s];
        acc8(a0, a1, u0);
    }
    a0.x += b0.x; a0.y += b0.y; a0.z += b0.z; a0.w += b0.w;
    a1.x += b1.x; a1.y += b1.y; a1.z += b1.z; a1.w += b1.w;

    float d = dinv[r];
    if (!last) {
        float d2 = d * d;
        uint4 h;
        h.x = h2u(__floats2half2_rn(d2 * a0.x, d2 * a0.y));
        h.y = h2u(__floats2half2_rn(d2 * a0.z, d2 * a0.w));
        h.z = h2u(__floats2half2_rn(d2 * a1.x, d2 * a1.y));
        h.w = h2u(__floats2half2_rn(d2 * a1.z, d2 * a1.w));
        ntstore_u4(&y[(size_t)r * 8 + s], h);
        return;
    }

    // ---- final combine: out = 0.25*(e0 + (hs1 + hs2)*inv_d + d*a3) ----
    float inv = 1.0f / d;
    uint4 u1 = h1s[(size_t)r * 8 + s];         // hs1 = d*h1 (fp16)
    uint4 u2v = x[(size_t)r * 8 + s];          // hs2 = d*h2 (fp16)
    float4 s0 = {0.f, 0.f, 0.f, 0.f}, s1 = {0.f, 0.f, 0.f, 0.f};
    acc8(s0, s1, u1);
    acc8(s0, s1, u2v);
    size_t fo = (size_t)r * 16 + s * 2;
    float4 e0a, e0b;
    if (r < U_CNT) { e0a = ntload_f4(&ue[fo]); e0b = ntload_f4(&ue[fo + 1]); }
    else { size_t io = fo - (size_t)U_CNT * 16; e0a = ntload_f4(&ie[io]); e0b = ntload_f4(&ie[io + 1]); }
    float4 o0, o1;
    o0.x = 0.25f * (e0a.x + inv * s0.x + d * a0.x);
    o0.y = 0.25f * (e0a.y + inv * s0.y + d * a0.y);
    o0.z = 0.25f * (e0a.z + inv * s0.z + d * a0.z);
    o0.w = 0.25f * (e0a.w + inv * s0.w + d * a0.w);
    o1.x = 0.25f * (e0b.x + inv * s1.x + d * a1.x);
    o1.y = 0.25f * (e0b.y + inv * s1.y + d * a1.y);
    o1.z = 0.25f * (e0b.z + inv * s1.z + d * a1.z);
    o1.w = 0.25f * (e0b.w + inv * s1.w + d * a1.w);
    ntstore_f4(&acc[fo], o0);
    ntstore_f4(&acc[fo + 1], o1);
}

extern "C" void kernel_launch(void* const* d_in, const int* in_sizes, int n_in,
                              void* d_out, int out_size, void* d_ws, size_t ws_size,
                              hipStream_t stream) {
    const float* ue   = (const float*)d_in[0];
    const float* ie   = (const float*)d_in[1];
    const int*   rows = (const int*)d_in[2];
    const int*   cols = (const int*)d_in[3];
    int nnz = in_sizes[2];
    int nchunk = (nnz + CH - 1) / CH;

    float* acc = (float*)d_out;

    unsigned int* ws = (unsigned int*)d_ws;
    uint4* hs0 = (uint4*)ws;                               // N*8 uint4 (fp16 hs)
    uint4* hs1 = hs0 + (size_t)N_CNT * 8;                  // N*8 uint4
    int*   row_ptr    = (int*)(hs1 + (size_t)N_CNT * 8);   // N+1
    int*   bhist      = row_ptr + (N_CNT + 1);             // NB2
    int*   bucket_ptr = bhist + NB2;                       // NB2+1
    float* dinv       = (float*)(bucket_ptr + NB2 + 1);    // N
    unsigned int* staging = (unsigned int*)(dinv + N_CNT); // nnz
    unsigned int* col_s   = staging + nnz;                 // nnz
    // cnt + ex2 overlay the col_s region (dead before binplace writes col_s)
    int* cnt = (int*)col_s;                                // nchunk*NB2R
    int* ex2 = cnt + (size_t)nchunk * NB2R;                // NB2*nchunk

    const int tpb = 256;

    // ---- CSR build: counts -> chunk scans -> bucket scan -> fill -> place ----
    count_kernel<<<nchunk, tpb, 0, stream>>>(rows, cnt, nnz);
    scan_chunks<<<NB2, tpb, 0, stream>>>(cnt, ex2, bhist, nchunk);
    bucket_scan<<<1, tpb, 0, stream>>>(bhist, bucket_ptr);
    fill_kernel<<<nchunk, tpb, 0, stream>>>(
        rows, cols, cnt, ex2, bucket_ptr, staging, nnz, nchunk);
    binplace_kernel<<<NB2, tpb, 0, stream>>>(
        bucket_ptr, staging, col_s, row_ptr, dinv);

    // ---- dinv-scaled initial embeddings ----
    init_kernel<<<(N_CNT * 8 + tpb - 1) / tpb, tpb, 0, stream>>>(
        (const float4*)ue, (const float4*)ie, dinv, hs0);

    // ---- 3 propagation layers, split user/item for L2 locality ----
    uint4* cur_h = hs0;
    uint4* nxt_h = hs1;
    const int ublocks = (U_CNT + 31) / 32;
    const int iblocks = (N_CNT - U_CNT + 31) / 32;
    for (int l = 0; l < 3; ++l) {
        int last = (l == 2) ? 1 : 0;
        // after L2 swap: cur_h holds hs2, nxt_h holds hs1 (needed for combine)
        spmm_gather<<<ublocks, tpb, 0, stream>>>(
            row_ptr, col_s, dinv, cur_h, nxt_h, nxt_h,
            (const float4*)ue, (const float4*)ie, (float4*)acc, 0, U_CNT, last);
        spmm_gather<<<iblocks, tpb, 0, stream>>>(
            row_ptr, col_s, dinv, cur_h, nxt_h, nxt_h,
            (const float4*)ue, (const float4*)ie, (float4*)acc, U_CNT, N_CNT, last);
        uint4* tmp = cur_h; cur_h = nxt_h; nxt_h = tmp;
    }
}